// Round 5
// baseline (286.544 us; speedup 1.0000x reference)
//
#include <hip/hip_runtime.h>
#include <math.h>

#define BLK 256
#define EPT 4   // elements per thread; grid = B / (BLK*EPT) = 2048 one-shot

// clang native vector type: __builtin_nontemporal_* requires this (NOT the
// HIP_vector_type class float4).
typedef float v4f __attribute__((ext_vector_type(4)));

__device__ __forceinline__ v4f nt4(const float* p) {
    return __builtin_nontemporal_load(reinterpret_cast<const v4f*>(p));
}

// Per-element math (identical numerics to the round-3 passing kernel).
__device__ __forceinline__ float compute_elem(
    float l1x, float l1y, float l1z, float l2x, float l2y, float l2z,
    float s1a, float s1b, float s1c, float s2a, float s2b, float s2c,
    const float* __restrict__ R1, const float* __restrict__ R2)
{
    const float dx = l1x - l2x, dy = l1y - l2y, dz = l1z - l2z;
    const float loc_diff2 = dx * dx + dy * dy + dz * dz;

    // M2 = R2 diag(s2) R2^T  (symmetric; 6 unique entries)
    const float m00 = s2a * R2[0] * R2[0] + s2b * R2[1] * R2[1] + s2c * R2[2] * R2[2];
    const float m01 = s2a * R2[0] * R2[3] + s2b * R2[1] * R2[4] + s2c * R2[2] * R2[5];
    const float m02 = s2a * R2[0] * R2[6] + s2b * R2[1] * R2[7] + s2c * R2[2] * R2[8];
    const float m11 = s2a * R2[3] * R2[3] + s2b * R2[4] * R2[4] + s2c * R2[5] * R2[5];
    const float m12 = s2a * R2[3] * R2[6] + s2b * R2[4] * R2[7] + s2c * R2[5] * R2[8];
    const float m22 = s2a * R2[6] * R2[6] + s2b * R2[7] * R2[7] + s2c * R2[8] * R2[8];

    // A = M2 * R1
    float A[9];
    A[0] = m00 * R1[0] + m01 * R1[3] + m02 * R1[6];
    A[1] = m00 * R1[1] + m01 * R1[4] + m02 * R1[7];
    A[2] = m00 * R1[2] + m01 * R1[5] + m02 * R1[8];
    A[3] = m01 * R1[0] + m11 * R1[3] + m12 * R1[6];
    A[4] = m01 * R1[1] + m11 * R1[4] + m12 * R1[7];
    A[5] = m01 * R1[2] + m11 * R1[5] + m12 * R1[8];
    A[6] = m02 * R1[0] + m12 * R1[3] + m22 * R1[6];
    A[7] = m02 * R1[1] + m12 * R1[4] + m22 * R1[7];
    A[8] = m02 * R1[2] + m12 * R1[5] + m22 * R1[8];

    // T = R1^T * A
    float T[9];
    T[0] = R1[0] * A[0] + R1[3] * A[3] + R1[6] * A[6];
    T[1] = R1[0] * A[1] + R1[3] * A[4] + R1[6] * A[7];
    T[2] = R1[0] * A[2] + R1[3] * A[5] + R1[6] * A[8];
    T[3] = R1[1] * A[0] + R1[4] * A[3] + R1[7] * A[6];
    T[4] = R1[1] * A[1] + R1[4] * A[4] + R1[7] * A[7];
    T[5] = R1[1] * A[2] + R1[4] * A[5] + R1[7] * A[8];
    T[6] = R1[2] * A[0] + R1[5] * A[3] + R1[8] * A[6];
    T[7] = R1[2] * A[1] + R1[5] * A[4] + R1[8] * A[7];
    T[8] = R1[2] * A[2] + R1[5] * A[5] + R1[8] * A[8];

    // E = diag(sqrt(s1)) T diag(sqrt(s1)), symmetrized
    const float sq0 = __builtin_amdgcn_sqrtf(s1a);
    const float sq1 = __builtin_amdgcn_sqrtf(s1b);
    const float sq2 = __builtin_amdgcn_sqrtf(s1c);
    const float e00 = s1a * T[0];
    const float e11 = s1b * T[4];
    const float e22 = s1c * T[8];
    const float e01 = 0.5f * sq0 * sq1 * (T[1] + T[3]);
    const float e02 = 0.5f * sq0 * sq2 * (T[2] + T[6]);
    const float e12 = 0.5f * sq1 * sq2 * (T[5] + T[7]);

    // Analytic eigenvalues of symmetric 3x3 (trigonometric / Smith's method)
    const float q  = (e00 + e11 + e22) * (1.0f / 3.0f);
    const float p1 = e01 * e01 + e02 * e02 + e12 * e12;
    const float d0 = e00 - q, d1 = e11 - q, d2 = e22 - q;
    const float p2 = d0 * d0 + d1 * d1 + d2 * d2 + 2.0f * p1;

    float trace_sqrt;
    if (p2 > 1e-24f) {
        const float p   = __builtin_amdgcn_sqrtf(p2 * (1.0f / 6.0f));
        const float inv = __builtin_amdgcn_rcpf(p);
        const float b00 = d0 * inv, b11 = d1 * inv, b22 = d2 * inv;
        const float b01 = e01 * inv, b02 = e02 * inv, b12 = e12 * inv;
        float detB = b00 * (b11 * b22 - b12 * b12)
                   - b01 * (b01 * b22 - b12 * b02)
                   + b02 * (b01 * b12 - b11 * b02);
        float r = 0.5f * detB;
        r = fminf(fmaxf(r, -1.0f), 1.0f);

        // acos(r) via Hastings approximation (|err| ~ 7e-5 rad), branchless
        const float ax = fabsf(r);
        const float z  = __builtin_amdgcn_sqrtf(1.0f - ax);
        const float w  = z * (1.5707288f + ax * (-0.2121144f
                           + ax * (0.0742610f + ax * (-0.0187293f))));
        const float ac = (r >= 0.0f) ? w : (3.14159265358979f - w);

        const float phi = ac * (1.0f / 3.0f);
        const float c   = __cosf(phi);
        const float s   = __sinf(phi);
        const float twop = 2.0f * p;
        const float eig1 = q + twop * c;
        const float eig3 = q + twop * (-0.5f * c - 0.86602540378f * s);
        const float eig2 = 3.0f * q - eig1 - eig3;
        trace_sqrt = __builtin_amdgcn_sqrtf(fabsf(eig1))
                   + __builtin_amdgcn_sqrtf(fabsf(eig2))
                   + __builtin_amdgcn_sqrtf(fabsf(eig3));
    } else {
        trace_sqrt = 3.0f * __builtin_amdgcn_sqrtf(fabsf(q));
    }

    float cov_w = (s1a + s1b + s1c) + (s2a + s2b + s2c) - 2.0f * trace_sqrt;
    cov_w = fmaxf(cov_w, 0.0f);
    return __builtin_amdgcn_sqrtf(loc_diff2 + cov_w);
}

__global__ __launch_bounds__(BLK, 2) void wasserstein_kernel(
    const float* __restrict__ loc1,   const float* __restrict__ scale1,
    const float* __restrict__ rot1,   const float* __restrict__ loc2,
    const float* __restrict__ scale2, const float* __restrict__ rot2,
    float* __restrict__ out)
{
    // Thread t owns 4 CONSECUTIVE elements [e0, e0+4). All its input data is
    // exactly 30 float4s at 16B-aligned addresses (48B/144B per-thread stride,
    // wave covers contiguous slabs). Issue ALL 30 independent nontemporal
    // loads into named registers FIRST -> up to 30 loads in flight per wave,
    // consumed with counted vmcnt waits. No LDS, no barriers, no reuse.
    const long long t  = (long long)blockIdx.x * BLK + threadIdx.x;
    const long long e0 = t * EPT;

    const float* gL1 = loc1   + e0 * 3;  // 3 float4s
    const float* gL2 = loc2   + e0 * 3;  // 3
    const float* gS1 = scale1 + e0 * 3;  // 3
    const float* gS2 = scale2 + e0 * 3;  // 3
    const float* gR1 = rot1   + e0 * 9;  // 9
    const float* gR2 = rot2   + e0 * 9;  // 9

    // ---- the load batch: 30 independent float4 loads ----
    const v4f r2a = nt4(gR2 +  0), r2b = nt4(gR2 +  4), r2c = nt4(gR2 +  8);
    const v4f r2d = nt4(gR2 + 12), r2e = nt4(gR2 + 16), r2f = nt4(gR2 + 20);
    const v4f r2g = nt4(gR2 + 24), r2h = nt4(gR2 + 28), r2i = nt4(gR2 + 32);
    const v4f r1a = nt4(gR1 +  0), r1b = nt4(gR1 +  4), r1c = nt4(gR1 +  8);
    const v4f r1d = nt4(gR1 + 12), r1e = nt4(gR1 + 16), r1f = nt4(gR1 + 20);
    const v4f r1g = nt4(gR1 + 24), r1h = nt4(gR1 + 28), r1i = nt4(gR1 + 32);
    const v4f s2x = nt4(gS2 + 0), s2y = nt4(gS2 + 4), s2z = nt4(gS2 + 8);
    const v4f s1x = nt4(gS1 + 0), s1y = nt4(gS1 + 4), s1z = nt4(gS1 + 8);
    const v4f l1a = nt4(gL1 + 0), l1b = nt4(gL1 + 4), l1c = nt4(gL1 + 8);
    const v4f l2a = nt4(gL2 + 0), l2b = nt4(gL2 + 4), l2c = nt4(gL2 + 8);

    // ---- unpack to flat arrays with compile-time indices ----
    float L1[12], L2[12], S1[12], S2[12], Q1[36], Q2[36];
    {
        const v4f a[3] = {l1a, l1b, l1c};
        const v4f b[3] = {l2a, l2b, l2c};
        const v4f c[3] = {s1x, s1y, s1z};
        const v4f d[3] = {s2x, s2y, s2z};
#pragma unroll
        for (int j = 0; j < 3; ++j) {
#pragma unroll
            for (int q = 0; q < 4; ++q) {
                L1[4*j+q] = a[j][q];
                L2[4*j+q] = b[j][q];
                S1[4*j+q] = c[j][q];
                S2[4*j+q] = d[j][q];
            }
        }
        const v4f e[9] = {r1a, r1b, r1c, r1d, r1e, r1f, r1g, r1h, r1i};
        const v4f f[9] = {r2a, r2b, r2c, r2d, r2e, r2f, r2g, r2h, r2i};
#pragma unroll
        for (int j = 0; j < 9; ++j) {
#pragma unroll
            for (int q = 0; q < 4; ++q) {
                Q1[4*j+q] = e[j][q];
                Q2[4*j+q] = f[j][q];
            }
        }
    }

    // ---- compute 4 elements (fully unrolled, constant indices) ----
    float of[EPT];
#pragma unroll
    for (int k = 0; k < EPT; ++k) {
        of[k] = compute_elem(
            L1[3*k], L1[3*k+1], L1[3*k+2],
            L2[3*k], L2[3*k+1], L2[3*k+2],
            S1[3*k], S1[3*k+1], S1[3*k+2],
            S2[3*k], S2[3*k+1], S2[3*k+2],
            Q1 + 9*k, Q2 + 9*k);
    }

    v4f o;
    o[0] = of[0]; o[1] = of[1]; o[2] = of[2]; o[3] = of[3];
    __builtin_nontemporal_store(o, reinterpret_cast<v4f*>(out + e0));
}

extern "C" void kernel_launch(void* const* d_in, const int* in_sizes, int n_in,
                              void* d_out, int out_size, void* d_ws, size_t ws_size,
                              hipStream_t stream) {
    const float* loc1   = (const float*)d_in[0];
    const float* scale1 = (const float*)d_in[1];
    const float* rot1   = (const float*)d_in[2];
    const float* loc2   = (const float*)d_in[3];
    const float* scale2 = (const float*)d_in[4];
    const float* rot2   = (const float*)d_in[5];
    float* out = (float*)d_out;

    const int B = in_sizes[0] / 3;          // 2097152
    const int grid = B / (BLK * EPT);       // 2048, exact

    wasserstein_kernel<<<grid, BLK, 0, stream>>>(loc1, scale1, rot1,
                                                 loc2, scale2, rot2, out);
}

// Round 6
// 242.646 us; speedup vs baseline: 1.1809x; 1.1809x over previous
//
#include <hip/hip_runtime.h>
#include <math.h>

#define BLK  256
#define GRID 2048   // 8 blocks/CU x 256 CU; B/(GRID*BLK) = 4 iterations/thread

// 12-byte, 4-aligned POD -> global_load_dwordx3.
struct F3 { float x, y, z; };

__device__ __forceinline__ F3 ldF3(const float* p) {
    F3 r; r.x = p[0]; r.y = p[1]; r.z = p[2]; return r;
}

__device__ __forceinline__ float compute_elem(
    const F3 L1, const F3 L2, const F3 S1, const F3 S2,
    const F3 r1a, const F3 r1b, const F3 r1c,
    const F3 r2a, const F3 r2b, const F3 r2c)
{
    const float dx = L1.x - L2.x, dy = L1.y - L2.y, dz = L1.z - L2.z;
    const float loc_diff2 = dx * dx + dy * dy + dz * dz;

    const float s1a = S1.x, s1b = S1.y, s1c = S1.z;
    const float s2a = S2.x, s2b = S2.y, s2c = S2.z;

    const float R1[9] = {r1a.x, r1a.y, r1a.z, r1b.x, r1b.y, r1b.z, r1c.x, r1c.y, r1c.z};
    const float R2[9] = {r2a.x, r2a.y, r2a.z, r2b.x, r2b.y, r2b.z, r2c.x, r2c.y, r2c.z};

    // M2 = R2 diag(s2) R2^T  (symmetric; 6 unique entries)
    const float m00 = s2a * R2[0] * R2[0] + s2b * R2[1] * R2[1] + s2c * R2[2] * R2[2];
    const float m01 = s2a * R2[0] * R2[3] + s2b * R2[1] * R2[4] + s2c * R2[2] * R2[5];
    const float m02 = s2a * R2[0] * R2[6] + s2b * R2[1] * R2[7] + s2c * R2[2] * R2[8];
    const float m11 = s2a * R2[3] * R2[3] + s2b * R2[4] * R2[4] + s2c * R2[5] * R2[5];
    const float m12 = s2a * R2[3] * R2[6] + s2b * R2[4] * R2[7] + s2c * R2[5] * R2[8];
    const float m22 = s2a * R2[6] * R2[6] + s2b * R2[7] * R2[7] + s2c * R2[8] * R2[8];

    // A = M2 * R1
    float A[9];
    A[0] = m00 * R1[0] + m01 * R1[3] + m02 * R1[6];
    A[1] = m00 * R1[1] + m01 * R1[4] + m02 * R1[7];
    A[2] = m00 * R1[2] + m01 * R1[5] + m02 * R1[8];
    A[3] = m01 * R1[0] + m11 * R1[3] + m12 * R1[6];
    A[4] = m01 * R1[1] + m11 * R1[4] + m12 * R1[7];
    A[5] = m01 * R1[2] + m11 * R1[5] + m12 * R1[8];
    A[6] = m02 * R1[0] + m12 * R1[3] + m22 * R1[6];
    A[7] = m02 * R1[1] + m12 * R1[4] + m22 * R1[7];
    A[8] = m02 * R1[2] + m12 * R1[5] + m22 * R1[8];

    // T = R1^T * A
    float T[9];
    T[0] = R1[0] * A[0] + R1[3] * A[3] + R1[6] * A[6];
    T[1] = R1[0] * A[1] + R1[3] * A[4] + R1[6] * A[7];
    T[2] = R1[0] * A[2] + R1[3] * A[5] + R1[6] * A[8];
    T[3] = R1[1] * A[0] + R1[4] * A[3] + R1[7] * A[6];
    T[4] = R1[1] * A[1] + R1[4] * A[4] + R1[7] * A[7];
    T[5] = R1[1] * A[2] + R1[4] * A[5] + R1[7] * A[8];
    T[6] = R1[2] * A[0] + R1[5] * A[3] + R1[8] * A[6];
    T[7] = R1[2] * A[1] + R1[5] * A[4] + R1[8] * A[7];
    T[8] = R1[2] * A[2] + R1[5] * A[5] + R1[8] * A[8];

    // E = diag(sqrt(s1)) T diag(sqrt(s1)), symmetrized
    const float sq0 = __builtin_amdgcn_sqrtf(s1a);
    const float sq1 = __builtin_amdgcn_sqrtf(s1b);
    const float sq2 = __builtin_amdgcn_sqrtf(s1c);
    const float e00 = s1a * T[0];
    const float e11 = s1b * T[4];
    const float e22 = s1c * T[8];
    const float e01 = 0.5f * sq0 * sq1 * (T[1] + T[3]);
    const float e02 = 0.5f * sq0 * sq2 * (T[2] + T[6]);
    const float e12 = 0.5f * sq1 * sq2 * (T[5] + T[7]);

    // Analytic eigenvalues of symmetric 3x3 (trigonometric / Smith's method)
    const float q  = (e00 + e11 + e22) * (1.0f / 3.0f);
    const float p1 = e01 * e01 + e02 * e02 + e12 * e12;
    const float d0 = e00 - q, d1 = e11 - q, d2 = e22 - q;
    const float p2 = d0 * d0 + d1 * d1 + d2 * d2 + 2.0f * p1;

    float trace_sqrt;
    if (p2 > 1e-24f) {
        const float p   = __builtin_amdgcn_sqrtf(p2 * (1.0f / 6.0f));
        const float inv = __builtin_amdgcn_rcpf(p);
        const float b00 = d0 * inv, b11 = d1 * inv, b22 = d2 * inv;
        const float b01 = e01 * inv, b02 = e02 * inv, b12 = e12 * inv;
        float detB = b00 * (b11 * b22 - b12 * b12)
                   - b01 * (b01 * b22 - b12 * b02)
                   + b02 * (b01 * b12 - b11 * b02);
        float r = 0.5f * detB;
        r = fminf(fmaxf(r, -1.0f), 1.0f);

        // acos(r) via Hastings approximation (|err| ~ 7e-5 rad), branchless
        const float ax = fabsf(r);
        const float z  = __builtin_amdgcn_sqrtf(1.0f - ax);
        const float w  = z * (1.5707288f + ax * (-0.2121144f
                           + ax * (0.0742610f + ax * (-0.0187293f))));
        const float ac = (r >= 0.0f) ? w : (3.14159265358979f - w);

        const float phi = ac * (1.0f / 3.0f);
        const float c   = __cosf(phi);
        const float s   = __sinf(phi);
        const float twop = 2.0f * p;
        const float eig1 = q + twop * c;
        const float eig3 = q + twop * (-0.5f * c - 0.86602540378f * s);
        const float eig2 = 3.0f * q - eig1 - eig3;
        trace_sqrt = __builtin_amdgcn_sqrtf(fabsf(eig1))
                   + __builtin_amdgcn_sqrtf(fabsf(eig2))
                   + __builtin_amdgcn_sqrtf(fabsf(eig3));
    } else {
        trace_sqrt = 3.0f * __builtin_amdgcn_sqrtf(fabsf(q));
    }

    float cov_w = (s1a + s1b + s1c) + (s2a + s2b + s2c) - 2.0f * trace_sqrt;
    cov_w = fmaxf(cov_w, 0.0f);
    return __builtin_amdgcn_sqrtf(loc_diff2 + cov_w);
}

// Persistent grid-stride kernel, m13-copy shape: 32 waves/CU static occupancy
// (GRID=2048 -> 8 blocks/CU; launch_bounds(256,8) pins VGPR<=64 -> 8 waves/SIMD).
// Per iteration: 10 independent dwordx3 loads -> one wait -> compute -> store.
// Latency hiding via wave-level TLP, not per-wave pipelining (rounds 3/5 showed
// the compiler destroys deep ILP batches; TLP is what the 6.3 TB/s copy uses).
__global__ __launch_bounds__(BLK, 8) void wasserstein_kernel(
    const float* __restrict__ loc1,   const float* __restrict__ scale1,
    const float* __restrict__ rot1,   const float* __restrict__ loc2,
    const float* __restrict__ scale2, const float* __restrict__ rot2,
    float* __restrict__ out, int B)
{
    const long long stride = (long long)GRID * BLK;
    const long long start  = (long long)blockIdx.x * BLK + threadIdx.x;

    for (long long i = start; i < B; i += stride) {
        // 10 independent loads, all issued before any use.
        const F3 L1  = ldF3(loc1   + i * 3);
        const F3 L2  = ldF3(loc2   + i * 3);
        const F3 S1  = ldF3(scale1 + i * 3);
        const F3 S2  = ldF3(scale2 + i * 3);
        const F3 r1a = ldF3(rot1 + i * 9);
        const F3 r1b = ldF3(rot1 + i * 9 + 3);
        const F3 r1c = ldF3(rot1 + i * 9 + 6);
        const F3 r2a = ldF3(rot2 + i * 9);
        const F3 r2b = ldF3(rot2 + i * 9 + 3);
        const F3 r2c = ldF3(rot2 + i * 9 + 6);

        out[i] = compute_elem(L1, L2, S1, S2, r1a, r1b, r1c, r2a, r2b, r2c);
    }
}

extern "C" void kernel_launch(void* const* d_in, const int* in_sizes, int n_in,
                              void* d_out, int out_size, void* d_ws, size_t ws_size,
                              hipStream_t stream) {
    const float* loc1   = (const float*)d_in[0];
    const float* scale1 = (const float*)d_in[1];
    const float* rot1   = (const float*)d_in[2];
    const float* loc2   = (const float*)d_in[3];
    const float* scale2 = (const float*)d_in[4];
    const float* rot2   = (const float*)d_in[5];
    float* out = (float*)d_out;

    const int B = in_sizes[0] / 3;   // 2097152

    wasserstein_kernel<<<GRID, BLK, 0, stream>>>(loc1, scale1, rot1,
                                                 loc2, scale2, rot2, out, B);
}

// Round 7
// 241.342 us; speedup vs baseline: 1.1873x; 1.0054x over previous
//
#include <hip/hip_runtime.h>
#include <math.h>

#define BLK    256
#define GRID   1024
#define EPT    8                   // B / (GRID*BLK)
#define STRIDE (GRID * BLK)        // 262144 elements

typedef float v2f __attribute__((ext_vector_type(2)));
typedef float v4f __attribute__((ext_vector_type(4)));

// One element's payload: 30 floats in named registers (never an indexed array).
struct Pay {
    v2f l1a; float l1z;
    v2f l2a; float l2z;
    v2f s1a; float s1z;
    v2f s2a; float s2z;
    v4f r1a; v4f r1b; float r1c;
    v4f r2a; v4f r2b; float r2c;
};

// 14 inline-asm loads (exact vmcnt bookkeeping; compiler inserts NO waits for
// asm outputs). saddr form: 32-bit byte offset VGPR + SGPR-pair base.
__device__ __forceinline__ void load_batch(Pay& p, unsigned off12, unsigned off36,
    const float* loc1, const float* loc2, const float* sc1, const float* sc2,
    const float* rot1, const float* rot2)
{
    asm volatile("global_load_dwordx2 %0, %1, %2"           : "=v"(p.l1a) : "v"(off12), "s"(loc1));
    asm volatile("global_load_dword   %0, %1, %2 offset:8"  : "=v"(p.l1z) : "v"(off12), "s"(loc1));
    asm volatile("global_load_dwordx2 %0, %1, %2"           : "=v"(p.l2a) : "v"(off12), "s"(loc2));
    asm volatile("global_load_dword   %0, %1, %2 offset:8"  : "=v"(p.l2z) : "v"(off12), "s"(loc2));
    asm volatile("global_load_dwordx2 %0, %1, %2"           : "=v"(p.s1a) : "v"(off12), "s"(sc1));
    asm volatile("global_load_dword   %0, %1, %2 offset:8"  : "=v"(p.s1z) : "v"(off12), "s"(sc1));
    asm volatile("global_load_dwordx2 %0, %1, %2"           : "=v"(p.s2a) : "v"(off12), "s"(sc2));
    asm volatile("global_load_dword   %0, %1, %2 offset:8"  : "=v"(p.s2z) : "v"(off12), "s"(sc2));
    asm volatile("global_load_dwordx4 %0, %1, %2"           : "=v"(p.r1a) : "v"(off36), "s"(rot1));
    asm volatile("global_load_dwordx4 %0, %1, %2 offset:16" : "=v"(p.r1b) : "v"(off36), "s"(rot1));
    asm volatile("global_load_dword   %0, %1, %2 offset:32" : "=v"(p.r1c) : "v"(off36), "s"(rot1));
    asm volatile("global_load_dwordx4 %0, %1, %2"           : "=v"(p.r2a) : "v"(off36), "s"(rot2));
    asm volatile("global_load_dwordx4 %0, %1, %2 offset:16" : "=v"(p.r2b) : "v"(off36), "s"(rot2));
    asm volatile("global_load_dword   %0, %1, %2 offset:32" : "=v"(p.r2c) : "v"(off36), "s"(rot2));
}

#define WAITV(N)  asm volatile("s_waitcnt vmcnt(" #N ")" ::: "memory")
#define SBAR()    __builtin_amdgcn_sched_barrier(0)

__device__ __forceinline__ void store_val(float v, unsigned off4, float* out) {
    asm volatile("global_store_dword %0, %1, %2" :: "v"(off4), "v"(v), "s"(out) : "memory");
}

__device__ __forceinline__ float compute_pay(const Pay& e)
{
    const float dx = e.l1a.x - e.l2a.x, dy = e.l1a.y - e.l2a.y, dz = e.l1z - e.l2z;
    const float loc_diff2 = dx * dx + dy * dy + dz * dz;

    const float s1a = e.s1a.x, s1b = e.s1a.y, s1c = e.s1z;
    const float s2a = e.s2a.x, s2b = e.s2a.y, s2c = e.s2z;

    const float R1[9] = {e.r1a.x, e.r1a.y, e.r1a.z, e.r1a.w,
                         e.r1b.x, e.r1b.y, e.r1b.z, e.r1b.w, e.r1c};
    const float R2[9] = {e.r2a.x, e.r2a.y, e.r2a.z, e.r2a.w,
                         e.r2b.x, e.r2b.y, e.r2b.z, e.r2b.w, e.r2c};

    // M2 = R2 diag(s2) R2^T  (symmetric; 6 unique entries)
    const float m00 = s2a * R2[0] * R2[0] + s2b * R2[1] * R2[1] + s2c * R2[2] * R2[2];
    const float m01 = s2a * R2[0] * R2[3] + s2b * R2[1] * R2[4] + s2c * R2[2] * R2[5];
    const float m02 = s2a * R2[0] * R2[6] + s2b * R2[1] * R2[7] + s2c * R2[2] * R2[8];
    const float m11 = s2a * R2[3] * R2[3] + s2b * R2[4] * R2[4] + s2c * R2[5] * R2[5];
    const float m12 = s2a * R2[3] * R2[6] + s2b * R2[4] * R2[7] + s2c * R2[5] * R2[8];
    const float m22 = s2a * R2[6] * R2[6] + s2b * R2[7] * R2[7] + s2c * R2[8] * R2[8];

    // A = M2 * R1
    float A[9];
    A[0] = m00 * R1[0] + m01 * R1[3] + m02 * R1[6];
    A[1] = m00 * R1[1] + m01 * R1[4] + m02 * R1[7];
    A[2] = m00 * R1[2] + m01 * R1[5] + m02 * R1[8];
    A[3] = m01 * R1[0] + m11 * R1[3] + m12 * R1[6];
    A[4] = m01 * R1[1] + m11 * R1[4] + m12 * R1[7];
    A[5] = m01 * R1[2] + m11 * R1[5] + m12 * R1[8];
    A[6] = m02 * R1[0] + m12 * R1[3] + m22 * R1[6];
    A[7] = m02 * R1[1] + m12 * R1[4] + m22 * R1[7];
    A[8] = m02 * R1[2] + m12 * R1[5] + m22 * R1[8];

    // T = R1^T * A
    float T[9];
    T[0] = R1[0] * A[0] + R1[3] * A[3] + R1[6] * A[6];
    T[1] = R1[0] * A[1] + R1[3] * A[4] + R1[6] * A[7];
    T[2] = R1[0] * A[2] + R1[3] * A[5] + R1[6] * A[8];
    T[3] = R1[1] * A[0] + R1[4] * A[3] + R1[7] * A[6];
    T[4] = R1[1] * A[1] + R1[4] * A[4] + R1[7] * A[7];
    T[5] = R1[1] * A[2] + R1[4] * A[5] + R1[7] * A[8];
    T[6] = R1[2] * A[0] + R1[5] * A[3] + R1[8] * A[6];
    T[7] = R1[2] * A[1] + R1[5] * A[4] + R1[8] * A[7];
    T[8] = R1[2] * A[2] + R1[5] * A[5] + R1[8] * A[8];

    // E = diag(sqrt(s1)) T diag(sqrt(s1)), symmetrized
    const float sq0 = __builtin_amdgcn_sqrtf(s1a);
    const float sq1 = __builtin_amdgcn_sqrtf(s1b);
    const float sq2 = __builtin_amdgcn_sqrtf(s1c);
    const float e00 = s1a * T[0];
    const float e11 = s1b * T[4];
    const float e22 = s1c * T[8];
    const float e01 = 0.5f * sq0 * sq1 * (T[1] + T[3]);
    const float e02 = 0.5f * sq0 * sq2 * (T[2] + T[6]);
    const float e12 = 0.5f * sq1 * sq2 * (T[5] + T[7]);

    // Analytic eigenvalues of symmetric 3x3 (trigonometric / Smith's method)
    const float q  = (e00 + e11 + e22) * (1.0f / 3.0f);
    const float p1 = e01 * e01 + e02 * e02 + e12 * e12;
    const float d0 = e00 - q, d1 = e11 - q, d2 = e22 - q;
    const float p2 = d0 * d0 + d1 * d1 + d2 * d2 + 2.0f * p1;

    float trace_sqrt;
    if (p2 > 1e-24f) {
        const float p   = __builtin_amdgcn_sqrtf(p2 * (1.0f / 6.0f));
        const float inv = __builtin_amdgcn_rcpf(p);
        const float b00 = d0 * inv, b11 = d1 * inv, b22 = d2 * inv;
        const float b01 = e01 * inv, b02 = e02 * inv, b12 = e12 * inv;
        float detB = b00 * (b11 * b22 - b12 * b12)
                   - b01 * (b01 * b22 - b12 * b02)
                   + b02 * (b01 * b12 - b11 * b02);
        float r = 0.5f * detB;
        r = fminf(fmaxf(r, -1.0f), 1.0f);

        // acos(r) via Hastings approximation (|err| ~ 7e-5 rad), branchless
        const float ax = fabsf(r);
        const float z  = __builtin_amdgcn_sqrtf(1.0f - ax);
        const float w  = z * (1.5707288f + ax * (-0.2121144f
                           + ax * (0.0742610f + ax * (-0.0187293f))));
        const float ac = (r >= 0.0f) ? w : (3.14159265358979f - w);

        const float phi = ac * (1.0f / 3.0f);
        const float c   = __cosf(phi);
        const float s   = __sinf(phi);
        const float twop = 2.0f * p;
        const float eig1 = q + twop * c;
        const float eig3 = q + twop * (-0.5f * c - 0.86602540378f * s);
        const float eig2 = 3.0f * q - eig1 - eig3;
        trace_sqrt = __builtin_amdgcn_sqrtf(fabsf(eig1))
                   + __builtin_amdgcn_sqrtf(fabsf(eig2))
                   + __builtin_amdgcn_sqrtf(fabsf(eig3));
    } else {
        trace_sqrt = 3.0f * __builtin_amdgcn_sqrtf(fabsf(q));
    }

    float cov_w = (s1a + s1b + s1c) + (s2a + s2b + s2c) - 2.0f * trace_sqrt;
    cov_w = fmaxf(cov_w, 0.0f);
    return __builtin_amdgcn_sqrtf(loc_diff2 + cov_w);
}

// Depth-2 hand-pipelined persistent kernel. Per wave, while computing element
// k, element k+1's 14 loads stay IN FLIGHT (counted vmcnt, never 0 in the
// loop) -> memory requests flow continuously instead of burst-drain-compute.
// Load/store ops are ALL inline asm so the vmcnt counts are exact.
__global__ __launch_bounds__(BLK, 4) void wasserstein_pipe(
    const float* __restrict__ loc1,   const float* __restrict__ scale1,
    const float* __restrict__ rot1,   const float* __restrict__ loc2,
    const float* __restrict__ scale2, const float* __restrict__ rot2,
    float* __restrict__ out)
{
    const unsigned i0 = blockIdx.x * BLK + threadIdx.x;
    unsigned offL12 = i0 * 12u, offL36 = i0 * 36u;
    unsigned offS4  = i0 * 4u;
    const unsigned D12 = STRIDE * 12u, D36 = STRIDE * 36u, D4 = STRIDE * 4u;

    Pay A, B;
    load_batch(A, offL12, offL36, loc1, loc2, scale1, scale2, rot1, rot2);
    offL12 += D12; offL36 += D36;
    load_batch(B, offL12, offL36, loc1, loc2, scale1, scale2, rot1, rot2);
    offL12 += D12; offL36 += D36;

    // Steady state: W(15) leaves {prev store, next batch(14)} outstanding.
#define STEP_LOAD(BUF)                                                        \
    WAITV(15); SBAR();                                                        \
    store_val(compute_pay(BUF), offS4, out); offS4 += D4;                     \
    load_batch(BUF, offL12, offL36, loc1, loc2, scale1, scale2, rot1, rot2);  \
    offL12 += D12; offL36 += D36;

    // k=0 (no prior store yet -> wait count 14)
    WAITV(14); SBAR();
    store_val(compute_pay(A), offS4, out); offS4 += D4;
    load_batch(A, offL12, offL36, loc1, loc2, scale1, scale2, rot1, rot2);
    offL12 += D12; offL36 += D36;

    STEP_LOAD(B)   // k=1 (loads elem 3 -> B)
    STEP_LOAD(A)   // k=2 (loads elem 4 -> A)
    STEP_LOAD(B)   // k=3 (loads elem 5 -> B)
    STEP_LOAD(A)   // k=4 (loads elem 6 -> A)
    STEP_LOAD(B)   // k=5 (loads elem 7 -> B)

    // k=6: compute A(elem 6); no more loads
    WAITV(15); SBAR();
    store_val(compute_pay(A), offS4, out); offS4 += D4;

    // k=7: only {prev store} may remain newer than batch 7
    WAITV(1); SBAR();
    store_val(compute_pay(B), offS4, out);
#undef STEP_LOAD
}

// Generic fallback (only used if B != STRIDE*EPT).
__global__ void wasserstein_simple(
    const float* __restrict__ loc1,   const float* __restrict__ scale1,
    const float* __restrict__ rot1,   const float* __restrict__ loc2,
    const float* __restrict__ scale2, const float* __restrict__ rot2,
    float* __restrict__ out, int B)
{
    long long i = (long long)blockIdx.x * blockDim.x + threadIdx.x;
    if (i >= B) return;
    Pay e;
    const float* p;
    p = loc1 + i * 3;   e.l1a.x = p[0]; e.l1a.y = p[1]; e.l1z = p[2];
    p = loc2 + i * 3;   e.l2a.x = p[0]; e.l2a.y = p[1]; e.l2z = p[2];
    p = scale1 + i * 3; e.s1a.x = p[0]; e.s1a.y = p[1]; e.s1z = p[2];
    p = scale2 + i * 3; e.s2a.x = p[0]; e.s2a.y = p[1]; e.s2z = p[2];
    p = rot1 + i * 9;
    e.r1a.x = p[0]; e.r1a.y = p[1]; e.r1a.z = p[2]; e.r1a.w = p[3];
    e.r1b.x = p[4]; e.r1b.y = p[5]; e.r1b.z = p[6]; e.r1b.w = p[7]; e.r1c = p[8];
    p = rot2 + i * 9;
    e.r2a.x = p[0]; e.r2a.y = p[1]; e.r2a.z = p[2]; e.r2a.w = p[3];
    e.r2b.x = p[4]; e.r2b.y = p[5]; e.r2b.z = p[6]; e.r2b.w = p[7]; e.r2c = p[8];
    out[i] = compute_pay(e);
}

extern "C" void kernel_launch(void* const* d_in, const int* in_sizes, int n_in,
                              void* d_out, int out_size, void* d_ws, size_t ws_size,
                              hipStream_t stream) {
    const float* loc1   = (const float*)d_in[0];
    const float* scale1 = (const float*)d_in[1];
    const float* rot1   = (const float*)d_in[2];
    const float* loc2   = (const float*)d_in[3];
    const float* scale2 = (const float*)d_in[4];
    const float* rot2   = (const float*)d_in[5];
    float* out = (float*)d_out;

    const int B = in_sizes[0] / 3;   // 2097152

    if (B == STRIDE * EPT) {
        wasserstein_pipe<<<GRID, BLK, 0, stream>>>(loc1, scale1, rot1,
                                                   loc2, scale2, rot2, out);
    } else {
        const int grid = (B + BLK - 1) / BLK;
        wasserstein_simple<<<grid, BLK, 0, stream>>>(loc1, scale1, rot1,
                                                     loc2, scale2, rot2, out, B);
    }
}